// Round 12
// baseline (237.249 us; speedup 1.0000x reference)
//
#include <hip/hip_runtime.h>
#include <math.h>

#define CF 768
#define MM 32
#define HW 784
#define MCF 24576
#define BETA 0.05f

typedef __attribute__((ext_vector_type(8))) short bf16x8;
typedef __attribute__((ext_vector_type(4))) float f32x4;

typedef union { unsigned int u[4]; bf16x8 v; } pk8u;

__device__ __forceinline__ unsigned short bf16rne(float x) {
    unsigned int bits = __float_as_uint(x);
    unsigned int r = (bits + 0x7fffu + ((bits >> 16) & 1u)) >> 16;
    return (unsigned short)r;
}
__device__ __forceinline__ float bf2f(unsigned short u) {
    return __uint_as_float(((unsigned int)u) << 16);
}
__device__ __forceinline__ float sigf(float x) { return 1.f / (1.f + __expf(-x)); }
__device__ __forceinline__ float ftanh(float x) {
    x = fminf(fmaxf(x, -12.f), 12.f);
    float e = __expf(2.f * x);
    return (e - 1.f) / (e + 1.f);
}
__device__ __forceinline__ void cvt8(const float4 a, const float4 b, unsigned short* u) {
    u[0] = bf16rne(a.x); u[1] = bf16rne(a.y); u[2] = bf16rne(a.z); u[3] = bf16rne(a.w);
    u[4] = bf16rne(b.x); u[5] = bf16rne(b.y); u[6] = bf16rne(b.z); u[7] = bf16rne(b.w);
}
// HW packed cvt: D = {bf16(hi)<<16 | bf16(lo)}. Used ONLY inside the einsum
// MFMA path where a potential lo/hi swap is order-consistent on both operands
// (dot product invariant), so it cannot corrupt results.
__device__ __forceinline__ unsigned int cvtpk(float lo, float hi) {
    unsigned int r;
    asm("v_cvt_pk_bf16_f32 %0, %1, %2" : "=v"(r) : "v"(lo), "v"(hi));
    return r;
}

// ================= kFE: merged front-end.
// blocks [0,768): einsum V[b][m][c], asm-pipelined global->reg MFMA fragments.
// blocks [768,2304): Wx -> bf16.  blocks [2304,4352): Wh -> bf16.
__global__ __launch_bounds__(256) void kFE(
    const float* __restrict__ F, const float* __restrict__ Ain,
    unsigned short* __restrict__ Vbf,
    const float* __restrict__ Wxi, const float* __restrict__ Wxf,
    const float* __restrict__ Wxo, const float* __restrict__ Wxc,
    unsigned short* __restrict__ Wxbf,
    const float* __restrict__ Whi, const float* __restrict__ Whf,
    const float* __restrict__ Who, const float* __restrict__ Whc,
    unsigned short* __restrict__ Wbf,
    float* __restrict__ outRC) {
    __shared__ float pls[2][2][64][4];   // [cw][mt][lane][reg] 4KB
    const int bid = blockIdx.x;
    const int t = threadIdx.x;

    if (bid >= 768) {
        if (bid == 768 && t == 0) outRC[0] = 0.f;
        if (bid < 2304) {
            int gid = (bid - 768) * 256 + t;
            int row = gid / 96;
            int kq = (gid - row * 96) * 8;
            int g = row >> 10, j = row & 1023;
            const float* Wg = (g == 0) ? Wxi : (g == 1) ? Wxf : (g == 2) ? Wxo : Wxc;
            const float* src = Wg + (size_t)j * CF + kq;
            float4 f0 = *(const float4*)src;
            float4 f1 = *(const float4*)(src + 4);
            unsigned short u[8];
            cvt8(f0, f1, u);
            *(uint4*)&Wxbf[(size_t)row * CF + kq] = *(const uint4*)u;
        } else {
            size_t tid8 = ((size_t)(bid - 2304) * 256 + t) * 8;
            int row = (int)(tid8 >> 10);
            int k = (int)(tid8 & 1023);
            int g = row >> 10, j = row & 1023;
            const float* Wg = (g == 0) ? Whi : (g == 1) ? Whf : (g == 2) ? Who : Whc;
            const float* src = Wg + (size_t)j * 1024 + k;
            float4 f0 = *(const float4*)src;
            float4 f1 = *(const float4*)(src + 4);
            unsigned short u[8];
            cvt8(f0, f1, u);
            *(uint4*)&Wbf[tid8] = *(const uint4*)u;
        }
        return;
    }

    // ---- einsum: block = (b, ct of 32 c); waves = (cw x 16c, kh K-parity)
    // k-chunks of 32: kh handles c = kh + 2i, i=0..11 (full) ; kh==0 also c=24 (partial).
    const int b = bid / 24, ct = bid - b * 24;
    const int cbase = ct * 32;
    const int lane = t & 63, w = t >> 6;
    const int cw = w & 1, kh = w >> 1;
    const int n = lane & 15, q = lane >> 4;

    const float* pF  = F + ((size_t)(b * CF) + cbase + cw * 16 + n) * HW + kh * 32 + q * 8;
    const float* pA0 = Ain + ((size_t)(b * 32 + n)) * HW + kh * 32 + q * 8;
    const float* pA1 = Ain + ((size_t)(b * 32 + 16 + n)) * HW + kh * 32 + q * 8;

    f32x4 acc0 = {0.f, 0.f, 0.f, 0.f};
    f32x4 acc1 = {0.f, 0.f, 0.f, 0.f};

    float4 bufA[6], bufB[6], bufC[6];

#define ISSUE(BUF, IMM)                                                                   \
    asm volatile("global_load_dwordx4 %0, %1, off offset:%2" : "=v"(BUF[0]) : "v"(pF),  "n"(IMM));      \
    asm volatile("global_load_dwordx4 %0, %1, off offset:%2" : "=v"(BUF[1]) : "v"(pF),  "n"(IMM + 16)); \
    asm volatile("global_load_dwordx4 %0, %1, off offset:%2" : "=v"(BUF[2]) : "v"(pA0), "n"(IMM));      \
    asm volatile("global_load_dwordx4 %0, %1, off offset:%2" : "=v"(BUF[3]) : "v"(pA0), "n"(IMM + 16)); \
    asm volatile("global_load_dwordx4 %0, %1, off offset:%2" : "=v"(BUF[4]) : "v"(pA1), "n"(IMM));      \
    asm volatile("global_load_dwordx4 %0, %1, off offset:%2" : "=v"(BUF[5]) : "v"(pA1), "n"(IMM + 16));

#define WAITP(N)                                              \
    asm volatile("s_waitcnt vmcnt(" #N ")" ::: "memory");     \
    __builtin_amdgcn_sched_barrier(0);

#define COMPP(BUF)                                                          \
    {                                                                       \
        pk8u uf_, u0_, u1_;                                                 \
        uf_.u[0] = cvtpk(BUF[0].x, BUF[0].y); uf_.u[1] = cvtpk(BUF[0].z, BUF[0].w); \
        uf_.u[2] = cvtpk(BUF[1].x, BUF[1].y); uf_.u[3] = cvtpk(BUF[1].z, BUF[1].w); \
        u0_.u[0] = cvtpk(BUF[2].x, BUF[2].y); u0_.u[1] = cvtpk(BUF[2].z, BUF[2].w); \
        u0_.u[2] = cvtpk(BUF[3].x, BUF[3].y); u0_.u[3] = cvtpk(BUF[3].z, BUF[3].w); \
        u1_.u[0] = cvtpk(BUF[4].x, BUF[4].y); u1_.u[1] = cvtpk(BUF[4].z, BUF[4].w); \
        u1_.u[2] = cvtpk(BUF[5].x, BUF[5].y); u1_.u[3] = cvtpk(BUF[5].z, BUF[5].w); \
        acc0 = __builtin_amdgcn_mfma_f32_16x16x32_bf16(u0_.v, uf_.v, acc0, 0, 0, 0); \
        acc1 = __builtin_amdgcn_mfma_f32_16x16x32_bf16(u1_.v, uf_.v, acc1, 0, 0, 0); \
    }

    // 12 full chunks, stride 2 chunks = 256 B; 2-deep pipeline, vmcnt counted.
    ISSUE(bufA, 0);
    ISSUE(bufB, 256);
    ISSUE(bufC, 512);  WAITP(12); COMPP(bufA);
    ISSUE(bufA, 768);  WAITP(12); COMPP(bufB);
    ISSUE(bufB, 1024); WAITP(12); COMPP(bufC);
    ISSUE(bufC, 1280); WAITP(12); COMPP(bufA);
    ISSUE(bufA, 1536); WAITP(12); COMPP(bufB);
    ISSUE(bufB, 1792); WAITP(12); COMPP(bufC);
    ISSUE(bufC, 2048); WAITP(12); COMPP(bufA);
    ISSUE(bufA, 2304); WAITP(12); COMPP(bufB);
    ISSUE(bufB, 2560); WAITP(12); COMPP(bufC);
    ISSUE(bufC, 2816); WAITP(12); COMPP(bufA);
    WAITP(6);  COMPP(bufB);
    WAITP(0);  COMPP(bufC);

#undef ISSUE
#undef WAITP
#undef COMPP

    // partial chunk c=24 (k in [768,784)) on kh==0, plain guarded loads (drained queue).
    if (kh == 0) {
        float4 tz = {0.f, 0.f, 0.f, 0.f};
        float4 tb[6] = {tz, tz, tz, tz, tz, tz};
        if (q < 2) {
            tb[0] = *(const float4*)(pF + 768);  tb[1] = *(const float4*)(pF + 772);
            tb[2] = *(const float4*)(pA0 + 768); tb[3] = *(const float4*)(pA0 + 772);
            tb[4] = *(const float4*)(pA1 + 768); tb[5] = *(const float4*)(pA1 + 772);
        }
        pk8u uf_, u0_, u1_;
        uf_.u[0] = cvtpk(tb[0].x, tb[0].y); uf_.u[1] = cvtpk(tb[0].z, tb[0].w);
        uf_.u[2] = cvtpk(tb[1].x, tb[1].y); uf_.u[3] = cvtpk(tb[1].z, tb[1].w);
        u0_.u[0] = cvtpk(tb[2].x, tb[2].y); u0_.u[1] = cvtpk(tb[2].z, tb[2].w);
        u0_.u[2] = cvtpk(tb[3].x, tb[3].y); u0_.u[3] = cvtpk(tb[3].z, tb[3].w);
        u1_.u[0] = cvtpk(tb[4].x, tb[4].y); u1_.u[1] = cvtpk(tb[4].z, tb[4].w);
        u1_.u[2] = cvtpk(tb[5].x, tb[5].y); u1_.u[3] = cvtpk(tb[5].z, tb[5].w);
        acc0 = __builtin_amdgcn_mfma_f32_16x16x32_bf16(u0_.v, uf_.v, acc0, 0, 0, 0);
        acc1 = __builtin_amdgcn_mfma_f32_16x16x32_bf16(u1_.v, uf_.v, acc1, 0, 0, 0);
    }

    if (kh == 1) {
        #pragma unroll
        for (int r = 0; r < 4; ++r) {
            pls[cw][0][lane][r] = acc0[r];
            pls[cw][1][lane][r] = acc1[r];
        }
    }
    __syncthreads();
    if (kh == 0) {
        #pragma unroll
        for (int r = 0; r < 4; ++r) {
            acc0[r] += pls[cw][0][lane][r];
            acc1[r] += pls[cw][1][lane][r];
        }
        #pragma unroll
        for (int r = 0; r < 4; ++r) {
            int m0 = q * 4 + r;
            Vbf[(size_t)(b * 32 + m0) * CF + cbase + cw * 16 + n] =
                bf16rne(acc0[r] * (1.f / 784.f));
            Vbf[(size_t)(b * 32 + 16 + m0) * CF + cbase + cw * 16 + n] =
                bf16rne(acc1[r] * (1.f / 784.f));
        }
    }
}

// ================= kC3B: MFMA GEMM Xbf = bf16( Vt @ Wx^T + bias )  (bx<16)
// + kB1/rcloss blocks (bx>=16): C_new + atomicAdd(outRC)
__global__ __launch_bounds__(512) void kC3B(
    const unsigned short* __restrict__ Vbf,
    const unsigned short* __restrict__ Wxbf,
    const float* __restrict__ bxi, const float* __restrict__ bxf,
    const float* __restrict__ bxo, const float* __restrict__ bxc,
    const float* __restrict__ bhi, const float* __restrict__ bhf,
    const float* __restrict__ bho, const float* __restrict__ bhc,
    unsigned short* __restrict__ Xbf,
    const float* __restrict__ C, float* __restrict__ Cnew_out,
    float* __restrict__ outRC) {
    __shared__ unsigned short Asg[512 * 8];
    const int bx = blockIdx.x;
    const int by = blockIdx.y;
    const int t = threadIdx.x;

    if (bx >= 16) {
        int e = (bx - 16) * 32 + by;
        if (e < 48) {
            int j = e * 512 + t;
            float c = C[j];
            float s = 0.f;
            #pragma unroll 4
            for (int b = 0; b < 32; ++b) s += bf2f(Vbf[(size_t)b * MCF + j]);
            float cn = c + BETA * (s * (1.f / 32.f) - c);
            Cnew_out[j] = cn;
            float ds = 0.f;
            #pragma unroll 4
            for (int b = 0; b < 32; ++b) {
                float d = bf2f(Vbf[(size_t)b * MCF + j]) - cn;
                ds = fmaf(d, d, ds);
            }
            float* red = (float*)Asg;
            red[t] = ds;
            __syncthreads();
            for (int off = 256; off > 0; off >>= 1) {
                if (t < off) red[t] += red[t + off];
                __syncthreads();
            }
            if (t == 0) atomicAdd(outRC, red[0] * (1.f / (32.f * 24576.f)));
        }
        return;
    }

    const int lane = t & 63;
    const int w = t >> 6;
    const int n = lane & 15;
    const int q = lane >> 4;
    const int mbase = bx * 64;

    const int st_row = (w & 3) * 16 + n;
    const int st_kb  = (w >> 2) * 4 + q;
    const int st_rg  = mbase + st_row;
    const int st_vrow = (st_rg & 31) * 32 + (st_rg >> 5);
    const unsigned short* st_src = Vbf + (size_t)st_vrow * CF + st_kb * 8;

    const int nb = by * 128 + w * 16;
    const unsigned short* Brow = Wxbf + (size_t)(nb + n) * CF + q * 8;

    f32x4 acc[4];
    #pragma unroll
    for (int g = 0; g < 4; ++g) acc[g] = (f32x4){0.f, 0.f, 0.f, 0.f};

    uint4 st = *(const uint4*)st_src;
    for (int kc = 0; kc < 12; ++kc) {
        __syncthreads();
        *(uint4*)&Asg[t * 8] = st;
        __syncthreads();
        if (kc + 1 < 12) st = *(const uint4*)(st_src + (kc + 1) * 64);
        #pragma unroll
        for (int p = 0; p < 2; ++p) {
            bf16x8 bfr = *(const bf16x8*)(Brow + kc * 64 + p * 32);
            #pragma unroll
            for (int g = 0; g < 4; ++g) {
                bf16x8 a = *(const bf16x8*)&Asg[((p * 4 + g) * 64 + lane) * 8];
                acc[g] = __builtin_amdgcn_mfma_f32_16x16x32_bf16(a, bfr, acc[g], 0, 0, 0);
            }
        }
    }

    const int gg = by >> 3;
    const int j = (by & 7) * 128 + w * 16 + n;
    const float* bx_ = (gg == 0) ? bxi : (gg == 1) ? bxf : (gg == 2) ? bxo : bxc;
    const float* bh_ = (gg == 0) ? bhi : (gg == 1) ? bhf : (gg == 2) ? bho : bhc;
    const float bias = bx_[j] + bh_[j];
    #pragma unroll
    for (int g = 0; g < 4; ++g) {
        #pragma unroll
        for (int rr = 0; rr < 4; ++rr) {
            int rg = mbase + g * 16 + q * 4 + rr;
            int tt = rg >> 5, bb = rg & 31;
            Xbf[((size_t)(tt * 4 + gg) * 32 + bb) * 1024 + j] = bf16rne(acc[g][rr] + bias);
        }
    }
}

// ================= kStep: one LSTM step. 256 blocks x 512 thr (8 waves).
__global__ __launch_bounds__(512) void kStep(
    const unsigned short* __restrict__ Wbf,
    const unsigned short* __restrict__ Xbf,
    const unsigned short* __restrict__ Hprev,
    unsigned short* __restrict__ Hnext,
    float* __restrict__ Cst,
    float* __restrict__ outH,
    int step) {
    __shared__ float pbuf[8][32][17];
    __shared__ float sbuf[32][17];
    const int bi = blockIdx.x;
    const int jbase = bi * 4;
    const int t = threadIdx.x;
    const int lane = t & 63;
    const int w = t >> 6;
    const int n = lane & 15;
    const int q = lane >> 4;

    const int pb = t >> 4, pnn = t & 15;
    const int pg = pnn >> 2, pjj = pnn & 3;
    const float xv = bf2f(Xbf[(((size_t)step * 4 + pg) * 32 + pb) * 1024 + jbase + pjj]);
    float cprev = 0.f;
    if (step > 0 && t < 128) cprev = Cst[(t >> 2) * 1024 + jbase + (t & 3)];

    if (step > 0) {
        const int g = n >> 2, jj = n & 3;
        const unsigned short* Wrow = Wbf + ((size_t)(g * 1024 + jbase + jj)) * 1024 + w * 128;
        const unsigned short* hb0 = Hprev + (size_t)n * 1024 + w * 128;
        const unsigned short* hb1 = Hprev + (size_t)(n + 16) * 1024 + w * 128;
        f32x4 acc0 = {0.f, 0.f, 0.f, 0.f};
        f32x4 acc1 = {0.f, 0.f, 0.f, 0.f};
        #pragma unroll
        for (int ks = 0; ks < 4; ++ks) {
            int k = ks * 32 + q * 8;
            bf16x8 bfrag = *(const bf16x8*)(Wrow + k);
            bf16x8 a0 = *(const bf16x8*)(hb0 + k);
            bf16x8 a1 = *(const bf16x8*)(hb1 + k);
            acc0 = __builtin_amdgcn_mfma_f32_16x16x32_bf16(a0, bfrag, acc0, 0, 0, 0);
            acc1 = __builtin_amdgcn_mfma_f32_16x16x32_bf16(a1, bfrag, acc1, 0, 0, 0);
        }
        #pragma unroll
        for (int r = 0; r < 4; ++r) {
            pbuf[w][q * 4 + r][n] = acc0[r];
            pbuf[w][16 + q * 4 + r][n] = acc1[r];
        }
    }
    __syncthreads();
    {
        float s = xv;
        if (step > 0) {
            #pragma unroll
            for (int w2 = 0; w2 < 8; ++w2) s += pbuf[w2][pb][pnn];
        }
        sbuf[pb][pnn] = s;
    }
    __syncthreads();
    if (t < 128) {
        int b = t >> 2, jj = t & 3;
        float I  = sigf(sbuf[b][jj]);
        float Fg = sigf(sbuf[b][4 + jj]);
        float O  = sigf(sbuf[b][8 + jj]);
        float Ct = ftanh(sbuf[b][12 + jj]);
        float c = fmaf(Fg, cprev, I * Ct);
        Cst[b * 1024 + jbase + jj] = c;
        float h = O * ftanh(c);
        if (step < 31) {
            Hnext[b * 1024 + jbase + jj] = bf16rne(h);
        } else {
            outH[b * 1024 + jbase + jj] = h;
        }
    }
}

extern "C" void kernel_launch(void* const* d_in, const int* in_sizes, int n_in,
                              void* d_out, int out_size, void* d_ws, size_t ws_size,
                              hipStream_t stream) {
    const float* F   = (const float*)d_in[0];
    const float* A   = (const float*)d_in[1];
    const float* C   = (const float*)d_in[2];
    const float* Wxi = (const float*)d_in[3];
    const float* bxi = (const float*)d_in[4];
    const float* Whi = (const float*)d_in[5];
    const float* bhi = (const float*)d_in[6];
    const float* Wxf = (const float*)d_in[7];
    const float* bxf = (const float*)d_in[8];
    const float* Whf = (const float*)d_in[9];
    const float* bhf = (const float*)d_in[10];
    const float* Wxo = (const float*)d_in[11];
    const float* bxo = (const float*)d_in[12];
    const float* Who = (const float*)d_in[13];
    const float* bho = (const float*)d_in[14];
    const float* Wxc = (const float*)d_in[15];
    const float* bxc = (const float*)d_in[16];
    const float* Whc = (const float*)d_in[17];
    const float* bhc = (const float*)d_in[18];

    float* out   = (float*)d_out;
    float* outH  = out;           // 32768
    float* outRC = out + 32768;   // 1
    float* outC  = out + 32769;   // 24576

    // ws layout (float units), ~25 MB:
    float* ws = (float*)d_ws;
    unsigned short* Xbf  = (unsigned short*)ws;                  // [0, 2097152)
    unsigned short* Wxbf = (unsigned short*)(ws + 2097152);      // [2097152, 3670016)
    unsigned short* Wbf  = (unsigned short*)(ws + 3670016);      // [3670016, 5767168)
    unsigned short* Vbf  = (unsigned short*)(ws + 5767168);      // [5767168, 6160384)
    unsigned short* Hbf  = (unsigned short*)(ws + 6160384);      // 2 x 32768 us
    float* Cst  = ws + 6193152;                                  // 32768

    kFE<<<dim3(4352), 256, 0, stream>>>(F, A, Vbf,
                                        Wxi, Wxf, Wxo, Wxc, Wxbf,
                                        Whi, Whf, Who, Whc, Wbf, outRC);
    kC3B<<<dim3(18, 32), 512, 0, stream>>>(Vbf, Wxbf,
                                           bxi, bxf, bxo, bxc,
                                           bhi, bhf, bho, bhc, Xbf,
                                           C, outC, outRC);

    for (int step = 0; step < 32; ++step) {
        const unsigned short* Hprev = Hbf + ((step + 1) & 1) * 32768;
        unsigned short* Hnext = (unsigned short*)(Hbf + (step & 1) * 32768);
        kStep<<<dim3(256), 512, 0, stream>>>(Wbf, Xbf, Hprev, Hnext, Cst, outH, step);
    }
}

// Round 13
// 228.108 us; speedup vs baseline: 1.0401x; 1.0401x over previous
//
#include <hip/hip_runtime.h>
#include <math.h>

#define CF 768
#define BB 32
#define MM 32
#define HW 784
#define NH 1024
#define MCF 24576
#define BETA 0.05f

typedef __attribute__((ext_vector_type(8))) short bf16x8;
typedef __attribute__((ext_vector_type(4))) float f32x4;

__device__ __forceinline__ unsigned short bf16rne(float x) {
    unsigned int bits = __float_as_uint(x);
    unsigned int r = (bits + 0x7fffu + ((bits >> 16) & 1u)) >> 16;
    return (unsigned short)r;
}
__device__ __forceinline__ float bf2f(unsigned short u) {
    return __uint_as_float(((unsigned int)u) << 16);
}
__device__ __forceinline__ float sigf(float x) { return 1.f / (1.f + __expf(-x)); }
__device__ __forceinline__ float ftanh(float x) {
    x = fminf(fmaxf(x, -12.f), 12.f);
    float e = __expf(2.f * x);
    return (e - 1.f) / (e + 1.f);
}

__device__ __forceinline__ void cvt8(const float4 a, const float4 b, unsigned short* u) {
    u[0] = bf16rne(a.x); u[1] = bf16rne(a.y); u[2] = bf16rne(a.z); u[3] = bf16rne(a.w);
    u[4] = bf16rne(b.x); u[5] = bf16rne(b.y); u[6] = bf16rne(b.z); u[7] = bf16rne(b.w);
}

// ================= kA3: MFMA einsum. V[b][m][c] = (1/784) sum_hw A[b][m][hw] F[b][c][hw]
// grid 384 = 32 b x 12 ctiles(64). 256 thr (4 waves, wave = n-tile of 16 c).
// K=784 zero-padded to 832 = 26 k-chunks of 32. A in frag-order LDS (once);
// F streamed in 64-k chunks (13), double-buffered, frag-order.
__global__ __launch_bounds__(256) void kA3(const float* __restrict__ F,
                                           const float* __restrict__ Ain,
                                           unsigned short* __restrict__ Vbf) {
    __shared__ unsigned short Alds[3328 * 8];      // 52 KB: slot16 = (kc*2+mt)*64+lane
    __shared__ unsigned short Flds[2][512 * 8];    // 2 x 8 KB: slot16 = (nt*2+kc2)*64+lane
    const int bid = blockIdx.x;
    const int b = bid / 12, ct = bid - b * 12;
    const int cbase = ct * 64;
    const int t = threadIdx.x;
    const int lane = t & 63, w = t >> 6;
    const int n = lane & 15, q = lane >> 4;

    // ---- A staging: slot s IS the target slot16 (linear writes, coalesced-ish reads)
    // decode: lf=s&63, mk=s>>6, mt=mk&1, kc=mk>>1, m=mt*16+(lf&15), k=kc*32+(lf>>4)*8
    {
        float4 va[7][2];
        #pragma unroll
        for (int it = 0; it < 7; ++it) {
            int s = it * 256 + t;
            int lf = s & 63, mk = s >> 6;
            int m = (mk & 1) * 16 + (lf & 15);
            int k = (mk >> 1) * 32 + (lf >> 4) * 8;
            if (k < 784) {
                const float* src = Ain + ((size_t)(b * 32 + m)) * 784 + k;
                va[it][0] = *(const float4*)src;
                va[it][1] = *(const float4*)(src + 4);
            } else {
                va[it][0] = (float4){0, 0, 0, 0};
                va[it][1] = (float4){0, 0, 0, 0};
            }
        }
        #pragma unroll
        for (int it = 0; it < 7; ++it) {
            int s = it * 256 + t;
            unsigned short u[8];
            cvt8(va[it][0], va[it][1], u);
            *(uint4*)&Alds[s * 8] = *(const uint4*)u;
        }
        float4 vb[6][2];
        #pragma unroll
        for (int it = 0; it < 6; ++it) {
            int s = (it + 7) * 256 + t;
            int lf = s & 63, mk = s >> 6;
            int m = (mk & 1) * 16 + (lf & 15);
            int k = (mk >> 1) * 32 + (lf >> 4) * 8;
            if (k < 784) {
                const float* src = Ain + ((size_t)(b * 32 + m)) * 784 + k;
                vb[it][0] = *(const float4*)src;
                vb[it][1] = *(const float4*)(src + 4);
            } else {
                vb[it][0] = (float4){0, 0, 0, 0};
                vb[it][1] = (float4){0, 0, 0, 0};
            }
        }
        #pragma unroll
        for (int it = 0; it < 6; ++it) {
            int s = (it + 7) * 256 + t;
            unsigned short u[8];
            cvt8(vb[it][0], vb[it][1], u);
            *(uint4*)&Alds[s * 8] = *(const uint4*)u;
        }
    }

    // ---- F chunk 0 prologue
    float4 pf[2][2];
    const int s0 = t, s1 = t + 256;
    const int ls0 = s0 & 63, kc20 = (s0 >> 6) & 1, nt0 = s0 >> 7;
    const int ls1 = s1 & 63, kc21 = (s1 >> 6) & 1, nt1 = s1 >> 7;
    const int fc0 = nt0 * 16 + (ls0 & 15), fk0 = kc20 * 32 + (ls0 >> 4) * 8;
    const int fc1 = nt1 * 16 + (ls1 & 15), fk1 = kc21 * 32 + (ls1 >> 4) * 8;
    const float* Fr0 = F + ((size_t)(b * 768) + cbase + fc0) * 784;
    const float* Fr1 = F + ((size_t)(b * 768) + cbase + fc1) * 784;
    pf[0][0] = *(const float4*)(Fr0 + fk0); pf[0][1] = *(const float4*)(Fr0 + fk0 + 4);
    pf[1][0] = *(const float4*)(Fr1 + fk1); pf[1][1] = *(const float4*)(Fr1 + fk1 + 4);
    {
        unsigned short u[8];
        cvt8(pf[0][0], pf[0][1], u); *(uint4*)&Flds[0][s0 * 8] = *(const uint4*)u;
        cvt8(pf[1][0], pf[1][1], u); *(uint4*)&Flds[0][s1 * 8] = *(const uint4*)u;
    }
    __syncthreads();

    f32x4 acc[2];
    acc[0] = (f32x4){0, 0, 0, 0};
    acc[1] = (f32x4){0, 0, 0, 0};

    for (int c13 = 0; c13 < 13; ++c13) {
        const int buf = c13 & 1;
        if (c13 < 12) {
            int k0 = (c13 + 1) * 64 + fk0;
            int k1 = (c13 + 1) * 64 + fk1;
            if (k0 < 784) {
                pf[0][0] = *(const float4*)(Fr0 + k0); pf[0][1] = *(const float4*)(Fr0 + k0 + 4);
            } else { pf[0][0] = (float4){0,0,0,0}; pf[0][1] = (float4){0,0,0,0}; }
            if (k1 < 784) {
                pf[1][0] = *(const float4*)(Fr1 + k1); pf[1][1] = *(const float4*)(Fr1 + k1 + 4);
            } else { pf[1][0] = (float4){0,0,0,0}; pf[1][1] = (float4){0,0,0,0}; }
        }
        #pragma unroll
        for (int kc2 = 0; kc2 < 2; ++kc2) {
            const int kc = c13 * 2 + kc2;
            bf16x8 bfr = *(const bf16x8*)&Flds[buf][((w * 2 + kc2) * 64 + lane) * 8];
            bf16x8 a0 = *(const bf16x8*)&Alds[((kc * 2 + 0) * 64 + lane) * 8];
            bf16x8 a1 = *(const bf16x8*)&Alds[((kc * 2 + 1) * 64 + lane) * 8];
            acc[0] = __builtin_amdgcn_mfma_f32_16x16x32_bf16(a0, bfr, acc[0], 0, 0, 0);
            acc[1] = __builtin_amdgcn_mfma_f32_16x16x32_bf16(a1, bfr, acc[1], 0, 0, 0);
        }
        if (c13 < 12) {
            unsigned short u[8];
            cvt8(pf[0][0], pf[0][1], u); *(uint4*)&Flds[buf ^ 1][s0 * 8] = *(const uint4*)u;
            cvt8(pf[1][0], pf[1][1], u); *(uint4*)&Flds[buf ^ 1][s1 * 8] = *(const uint4*)u;
        }
        __syncthreads();
    }

    #pragma unroll
    for (int mt = 0; mt < 2; ++mt)
        #pragma unroll
        for (int r = 0; r < 4; ++r)
            Vbf[(size_t)(b * 32 + mt * 16 + q * 4 + r) * 768 + cbase + w * 16 + n] =
                bf16rne(acc[mt][r] * (1.f / 784.f));
}

// ================= kMisc: kB1 (96 blocks) + prepX (1536) + prepH (2048)
__global__ __launch_bounds__(256) void kMisc(
    const unsigned short* __restrict__ Vbf, const float* __restrict__ C,
    float* __restrict__ Cnew_out, float* __restrict__ partial,
    const float* __restrict__ Wxi, const float* __restrict__ Wxf,
    const float* __restrict__ Wxo, const float* __restrict__ Wxc,
    unsigned short* __restrict__ Wxbf,
    const float* __restrict__ Whi, const float* __restrict__ Whf,
    const float* __restrict__ Who, const float* __restrict__ Whc,
    unsigned short* __restrict__ Wbf) {
    const int bid = blockIdx.x;
    if (bid < 96) {
        int j = bid * 256 + threadIdx.x;
        float c = C[j];
        float s = 0.f;
        for (int b = 0; b < 32; ++b) s += bf2f(Vbf[(size_t)b * MCF + j]);
        float cn = c + BETA * (s * (1.f / 32.f) - c);
        Cnew_out[j] = cn;
        float ds = 0.f;
        for (int b = 0; b < 32; ++b) {
            float d = bf2f(Vbf[(size_t)b * MCF + j]) - cn;
            ds = fmaf(d, d, ds);
        }
        __shared__ float red[256];
        red[threadIdx.x] = ds;
        __syncthreads();
        for (int off = 128; off > 0; off >>= 1) {
            if (threadIdx.x < off) red[threadIdx.x] += red[threadIdx.x + off];
            __syncthreads();
        }
        if (threadIdx.x == 0) partial[bid] = red[0];
    } else if (bid < 1632) {
        int gid = (bid - 96) * 256 + threadIdx.x;   // 393216
        int row = gid / 96;
        int kq = (gid - row * 96) * 8;
        int g = row >> 10, j = row & 1023;
        const float* Wg = (g == 0) ? Wxi : (g == 1) ? Wxf : (g == 2) ? Wxo : Wxc;
        const float* src = Wg + (size_t)j * CF + kq;
        float4 f0 = *(const float4*)src;
        float4 f1 = *(const float4*)(src + 4);
        unsigned short u[8];
        cvt8(f0, f1, u);
        *(uint4*)&Wxbf[(size_t)row * CF + kq] = *(const uint4*)u;
    } else {
        size_t tid8 = ((size_t)(bid - 1632) * 256 + threadIdx.x) * 8;
        int row = (int)(tid8 >> 10);
        int k = (int)(tid8 & 1023);
        int g = row >> 10, j = row & 1023;
        const float* Wg = (g == 0) ? Whi : (g == 1) ? Whf : (g == 2) ? Who : Whc;
        const float* src = Wg + (size_t)j * 1024 + k;
        float4 f0 = *(const float4*)src;
        float4 f1 = *(const float4*)(src + 4);
        unsigned short u[8];
        cvt8(f0, f1, u);
        *(uint4*)&Wbf[tid8] = *(const uint4*)u;
    }
}

// ================= kC3: MFMA GEMM  Xbf = bf16( Vt[1024x768] @ Wx^T[768x4096] + bias )
// + fused kB2 (rcloss final reduce) in block (0,31)
__global__ __launch_bounds__(512) void kC3(
    const unsigned short* __restrict__ Vbf,
    const unsigned short* __restrict__ Wxbf,
    const float* __restrict__ bxi, const float* __restrict__ bxf,
    const float* __restrict__ bxo, const float* __restrict__ bxc,
    const float* __restrict__ bhi, const float* __restrict__ bhf,
    const float* __restrict__ bho, const float* __restrict__ bhc,
    unsigned short* __restrict__ Xbf,
    const float* __restrict__ partial, float* __restrict__ outRC) {
    __shared__ unsigned short Asg[512 * 8];
    const int bx = blockIdx.x;
    const int by = blockIdx.y;
    const int t = threadIdx.x;
    const int lane = t & 63;
    const int w = t >> 6;
    const int n = lane & 15;
    const int q = lane >> 4;
    const int mbase = bx * 64;

    const int st_row = (w & 3) * 16 + n;
    const int st_kb  = (w >> 2) * 4 + q;
    const int st_rg  = mbase + st_row;
    const int st_vrow = (st_rg & 31) * 32 + (st_rg >> 5);
    const unsigned short* st_src = Vbf + (size_t)st_vrow * CF + st_kb * 8;

    const int nb = by * 128 + w * 16;
    const unsigned short* Brow = Wxbf + (size_t)(nb + n) * CF + q * 8;

    f32x4 acc[4];
    #pragma unroll
    for (int g = 0; g < 4; ++g) acc[g] = (f32x4){0.f, 0.f, 0.f, 0.f};

    uint4 st = *(const uint4*)st_src;
    for (int kc = 0; kc < 12; ++kc) {
        __syncthreads();
        *(uint4*)&Asg[t * 8] = st;
        __syncthreads();
        if (kc + 1 < 12) st = *(const uint4*)(st_src + (kc + 1) * 64);
        #pragma unroll
        for (int p = 0; p < 2; ++p) {
            bf16x8 bfr = *(const bf16x8*)(Brow + kc * 64 + p * 32);
            #pragma unroll
            for (int g = 0; g < 4; ++g) {
                bf16x8 a = *(const bf16x8*)&Asg[((p * 4 + g) * 64 + lane) * 8];
                acc[g] = __builtin_amdgcn_mfma_f32_16x16x32_bf16(a, bfr, acc[g], 0, 0, 0);
            }
        }
    }

    const int gg = by >> 3;
    const int j = (by & 7) * 128 + w * 16 + n;
    const float* bx_ = (gg == 0) ? bxi : (gg == 1) ? bxf : (gg == 2) ? bxo : bxc;
    const float* bh_ = (gg == 0) ? bhi : (gg == 1) ? bhf : (gg == 2) ? bho : bhc;
    const float bias = bx_[j] + bh_[j];
    #pragma unroll
    for (int g = 0; g < 4; ++g) {
        #pragma unroll
        for (int rr = 0; rr < 4; ++rr) {
            int rg = mbase + g * 16 + q * 4 + rr;
            int tt = rg >> 5, bb = rg & 31;
            Xbf[((size_t)(tt * 4 + gg) * 32 + bb) * 1024 + j] = bf16rne(acc[g][rr] + bias);
        }
    }

    // fused kB2: final rcloss reduce (uses Asg as f32 scratch)
    if (bx == 0 && by == 31) {
        __syncthreads();
        float* red = (float*)Asg;
        float v = (t < 96) ? partial[t] : 0.f;
        red[t] = v;
        __syncthreads();
        for (int off = 256; off > 0; off >>= 1) {
            if (t < off) red[t] += red[t + off];
            __syncthreads();
        }
        if (t == 0) outRC[0] = red[0] / (32.f * 24576.f);
    }
}

// ================= kStep: one LSTM step. 256 blocks x 512 thr (8 waves).
__global__ __launch_bounds__(512) void kStep(
    const unsigned short* __restrict__ Wbf,
    const unsigned short* __restrict__ Xbf,
    const unsigned short* __restrict__ Hprev,
    unsigned short* __restrict__ Hnext,
    float* __restrict__ Cst,
    float* __restrict__ outH,
    int step) {
    __shared__ float pbuf[8][32][17];
    __shared__ float sbuf[32][17];
    const int bi = blockIdx.x;
    const int jbase = bi * 4;
    const int t = threadIdx.x;
    const int lane = t & 63;
    const int w = t >> 6;
    const int n = lane & 15;
    const int q = lane >> 4;

    // prefetch (off the critical path): Xpre value + cell state
    const int pb = t >> 4, pnn = t & 15;
    const int pg = pnn >> 2, pjj = pnn & 3;
    const float xv = bf2f(Xbf[(((size_t)step * 4 + pg) * 32 + pb) * 1024 + jbase + pjj]);
    float cprev = 0.f;
    if (step > 0 && t < 128) cprev = Cst[(t >> 2) * 1024 + jbase + (t & 3)];

    if (step > 0) {
        const int g = n >> 2, jj = n & 3;
        const unsigned short* Wrow = Wbf + ((size_t)(g * 1024 + jbase + jj)) * 1024 + w * 128;
        const unsigned short* hb0 = Hprev + (size_t)n * 1024 + w * 128;
        const unsigned short* hb1 = Hprev + (size_t)(n + 16) * 1024 + w * 128;
        f32x4 acc0 = {0.f, 0.f, 0.f, 0.f};
        f32x4 acc1 = {0.f, 0.f, 0.f, 0.f};
        #pragma unroll
        for (int ks = 0; ks < 4; ++ks) {
            int k = ks * 32 + q * 8;
            bf16x8 bfrag = *(const bf16x8*)(Wrow + k);
            bf16x8 a0 = *(const bf16x8*)(hb0 + k);
            bf16x8 a1 = *(const bf16x8*)(hb1 + k);
            acc0 = __builtin_amdgcn_mfma_f32_16x16x32_bf16(a0, bfrag, acc0, 0, 0, 0);
            acc1 = __builtin_amdgcn_mfma_f32_16x16x32_bf16(a1, bfrag, acc1, 0, 0, 0);
        }
        #pragma unroll
        for (int r = 0; r < 4; ++r) {
            pbuf[w][q * 4 + r][n] = acc0[r];
            pbuf[w][16 + q * 4 + r][n] = acc1[r];
        }
    }
    __syncthreads();
    {
        float s = xv;
        if (step > 0) {
            #pragma unroll
            for (int w2 = 0; w2 < 8; ++w2) s += pbuf[w2][pb][pnn];
        }
        sbuf[pb][pnn] = s;
    }
    __syncthreads();
    if (t < 128) {
        int b = t >> 2, jj = t & 3;
        float I  = sigf(sbuf[b][jj]);
        float Fg = sigf(sbuf[b][4 + jj]);
        float O  = sigf(sbuf[b][8 + jj]);
        float Ct = ftanh(sbuf[b][12 + jj]);
        float c = fmaf(Fg, cprev, I * Ct);
        Cst[b * 1024 + jbase + jj] = c;
        float h = O * ftanh(c);
        if (step < 31) {
            Hnext[b * 1024 + jbase + jj] = bf16rne(h);
        } else {
            outH[b * 1024 + jbase + jj] = h;
        }
    }
}

extern "C" void kernel_launch(void* const* d_in, const int* in_sizes, int n_in,
                              void* d_out, int out_size, void* d_ws, size_t ws_size,
                              hipStream_t stream) {
    const float* F   = (const float*)d_in[0];
    const float* A   = (const float*)d_in[1];
    const float* C   = (const float*)d_in[2];
    const float* Wxi = (const float*)d_in[3];
    const float* bxi = (const float*)d_in[4];
    const float* Whi = (const float*)d_in[5];
    const float* bhi = (const float*)d_in[6];
    const float* Wxf = (const float*)d_in[7];
    const float* bxf = (const float*)d_in[8];
    const float* Whf = (const float*)d_in[9];
    const float* bhf = (const float*)d_in[10];
    const float* Wxo = (const float*)d_in[11];
    const float* bxo = (const float*)d_in[12];
    const float* Who = (const float*)d_in[13];
    const float* bho = (const float*)d_in[14];
    const float* Wxc = (const float*)d_in[15];
    const float* bxc = (const float*)d_in[16];
    const float* Whc = (const float*)d_in[17];
    const float* bhc = (const float*)d_in[18];

    float* out   = (float*)d_out;
    float* outH  = out;           // 32768
    float* outRC = out + 32768;   // 1
    float* outC  = out + 32769;   // 24576

    // ws layout (float units), ~24.9 MB:
    float* ws = (float*)d_ws;
    unsigned short* Xbf  = (unsigned short*)ws;                  // [0, 2097152)
    unsigned short* Wxbf = (unsigned short*)(ws + 2097152);      // [2097152, 3670016)
    unsigned short* Wbf  = (unsigned short*)(ws + 3670016);      // [3670016, 5767168)
    unsigned short* Vbf  = (unsigned short*)(ws + 5767168);      // [5767168, 6160384)
    float* part = ws + 6160384;                                  // 96
    unsigned short* Hbf = (unsigned short*)(ws + 6160480);       // 2 x 32768 us
    float* Cst  = ws + 6193248;                                  // 32768

    kA3<<<dim3(384), 256, 0, stream>>>(F, A, Vbf);
    kMisc<<<dim3(3680), 256, 0, stream>>>(Vbf, C, outC, part,
                                          Wxi, Wxf, Wxo, Wxc, Wxbf,
                                          Whi, Whf, Who, Whc, Wbf);
    kC3<<<dim3(16, 32), 512, 0, stream>>>(Vbf, Wxbf,
                                          bxi, bxf, bxo, bxc,
                                          bhi, bhf, bho, bhc, Xbf,
                                          part, outRC);

    for (int step = 0; step < 32; ++step) {
        const unsigned short* Hprev = Hbf + ((step + 1) & 1) * 32768;
        unsigned short* Hnext = (unsigned short*)(Hbf + (step & 1) * 32768);
        kStep<<<dim3(256), 512, 0, stream>>>(Wbf, Xbf, Hprev, Hnext, Cst, outH, step);
    }
}